// Round 6
// baseline (224.277 us; speedup 1.0000x reference)
//
#include <hip/hip_runtime.h>
#include <stdint.h>

#define CUBE_LEN   512
#define EQU_H      1024
#define EQU_W      2048
#define EQU_COUNT  4
#define CHANNELS   3
#define HW         (EQU_H * EQU_W)

typedef float f32x4 __attribute__((ext_vector_type(4)));
typedef float f32x2 __attribute__((ext_vector_type(2)));

// byte offset of image i = (e,c): e*18874368 + c*1048576
#define IMG_OFF(i) ((uint64_t)(((i) / 3) * 18874368u + ((i) % 3) * 1048576u))

// Round-12: round-5 bench died at container level (infra, not kernel:
// no loops -> cannot hang; all accesses proven in-bounds; divergent asm
// is plain exec-mask predication). Resubmitting round-11 unchanged.
//
// Round-11 theory: rounds 2+4 proved the floor is per-lane address
// processing in the vmem path (same ~90-97us under wildly different
// line-split and HBM traffic; 24 gathers x 64 lanes x 128 waves/CU at
// ~1 addr/cy = 94us). Fix: PIXEL-PAIR windows. Thread owns pixels
// (2t, 2t+1). One dwordx4 window [xm..xm+3] x 2 rows per image serves
// BOTH pixels' bilinear taps whenever (same face && same y0 &&
// |dx0|<=2) - true for ~85-90% of lanes (du/dw <= 1.6 everywhere).
// 24 gather lane-addrs per 2 px instead of 48; uv/face/stores halved.
// Incompatible lanes: masked fallback dwordx2 pair (TA skips inactive).
// X-blend = dot4 with select-built weight vector (branchless, built
// once, amortized over 12 images). Block=128 -> 8 blocks/row: round-2's
// proven vertical-strip XCD locality (round-4 tiling tripled FETCH).
__global__ __launch_bounds__(128, 1) void cube2equirec_kernel(
    const float* __restrict__ x,
    const float* __restrict__ uv,
    const int*   __restrict__ face,
    float*       __restrict__ out)
{
    const int tid = blockIdx.x * 128 + threadIdx.x;   // pixel-PAIR index

    const f32x4 uv4 = ((const f32x4*)uv)[tid];        // uA vA uB vB
    const int2  fpr = ((const int2*)face)[tid];
    const float uA = uv4.x, vA = uv4.y, uB = uv4.z, vB = uv4.w;
    const int   fA = fpr.x, fB = fpr.y;

    int x0A = (int)floorf(uA), y0A = (int)floorf(vA);
    int x0B = (int)floorf(uB), y0B = (int)floorf(vB);
    x0A = min(max(x0A, 0), 510); y0A = min(max(y0A, 0), 510);
    x0B = min(max(x0B, 0), 510); y0B = min(max(y0B, 0), 510);
    const float wxA = uA - (float)x0A, wyA = vA - (float)y0A;
    const float wxB = uB - (float)x0B, wyB = vB - (float)y0B;

    const int  xmw    = min(x0A, x0B);
    const bool compat = (fA == fB) && (y0A == y0B)
                     && ((max(x0A, x0B) - xmw) <= 2);
    // window base col; clamp 508 keeps dwordx4 inside the row (A always
    // covered: x0A<=510 -> x0A,x0A+1 in [508..511]).
    const int xm = min(compat ? xmw : x0A, 508);
    const int oA = x0A - xm;                          // 0..2
    const int oB = min(max(x0B - xm, 0), 2);          // clamped, garbage-safe

    const uint32_t vbW = (uint32_t)(fA * 3145728 + y0A * 2048 + xm * 4);
    const uint32_t vbB = (uint32_t)(fB * 3145728 + y0B * 2048 + x0B * 4);
    const uint64_t xb  = (uint64_t)x;

    // select-built x-weight vectors (once per thread, amortized x12 images)
    const float aL = 1.f - wxA, aR = wxA;
    const float bL = 1.f - wxB, bR = wxB;
    f32x4 WA, WB;
    WA.x = (oA == 0) ? aL : 0.f;
    WA.y = (oA == 0) ? aR : ((oA == 1) ? aL : 0.f);
    WA.z = (oA == 2) ? aL : ((oA == 1) ? aR : 0.f);
    WA.w = (oA == 2) ? aR : 0.f;
    WB.x = (oB == 0) ? bL : 0.f;
    WB.y = (oB == 0) ? bR : ((oB == 1) ? bL : 0.f);
    WB.z = (oB == 2) ? bL : ((oB == 1) ? bR : 0.f);
    WB.w = (oB == 2) ? bR : 0.f;
    const f32x4 WA0 = WA * (1.f - wyA), WA1 = WA * wyA;
    const f32x4 WB0 = WB * (1.f - wyB), WB1 = WB * wyB;
    // fallback scalar weights for B
    const float c00 = bL * (1.f - wyB), c01 = bR * (1.f - wyB);
    const float c10 = bL * wyB,         c11 = bR * wyB;

#define EMIT2(i, R0, R1, Q0, Q1)                                             \
    {                                                                        \
        const float ovA = R0.x * WA0.x + R0.y * WA0.y + R0.z * WA0.z         \
                        + R0.w * WA0.w + R1.x * WA1.x + R1.y * WA1.y         \
                        + R1.z * WA1.z + R1.w * WA1.w;                       \
        const float oBw = R0.x * WB0.x + R0.y * WB0.y + R0.z * WB0.z         \
                        + R0.w * WB0.w + R1.x * WB1.x + R1.y * WB1.y         \
                        + R1.z * WB1.z + R1.w * WB1.w;                       \
        const float oBf = Q0.x * c00 + Q0.y * c01 + Q1.x * c10 + Q1.y * c11; \
        f32x2 st;                                                            \
        st.x = ovA;                                                          \
        st.y = compat ? oBw : oBf;                                           \
        __builtin_nontemporal_store(st, (f32x2*)(out + (size_t)(i) * HW) + tid); \
    }

#define ROUND(I0)                                                            \
    {                                                                        \
        f32x4 r0_0, r1_0, r0_1, r1_1, r0_2, r1_2,                            \
              r0_3, r1_3, r0_4, r1_4, r0_5, r1_5;                            \
        asm volatile(                                                        \
            "global_load_dwordx4 %[a0], %[vb], %[s0]\n\t"                    \
            "global_load_dwordx4 %[b0], %[vb], %[s0] offset:2048\n\t"        \
            "global_load_dwordx4 %[a1], %[vb], %[s1]\n\t"                    \
            "global_load_dwordx4 %[b1], %[vb], %[s1] offset:2048\n\t"        \
            "global_load_dwordx4 %[a2], %[vb], %[s2]\n\t"                    \
            "global_load_dwordx4 %[b2], %[vb], %[s2] offset:2048\n\t"        \
            "global_load_dwordx4 %[a3], %[vb], %[s3]\n\t"                    \
            "global_load_dwordx4 %[b3], %[vb], %[s3] offset:2048\n\t"        \
            "global_load_dwordx4 %[a4], %[vb], %[s4]\n\t"                    \
            "global_load_dwordx4 %[b4], %[vb], %[s4] offset:2048\n\t"        \
            "global_load_dwordx4 %[a5], %[vb], %[s5]\n\t"                    \
            "global_load_dwordx4 %[b5], %[vb], %[s5] offset:2048"            \
            : [a0] "=&v"(r0_0), [b0] "=&v"(r1_0),                            \
              [a1] "=&v"(r0_1), [b1] "=&v"(r1_1),                            \
              [a2] "=&v"(r0_2), [b2] "=&v"(r1_2),                            \
              [a3] "=&v"(r0_3), [b3] "=&v"(r1_3),                            \
              [a4] "=&v"(r0_4), [b4] "=&v"(r1_4),                            \
              [a5] "=&v"(r0_5), [b5] "=&v"(r1_5)                             \
            : [vb] "v"(vbW),                                                 \
              [s0] "s"(xb + IMG_OFF((I0) + 0)),                              \
              [s1] "s"(xb + IMG_OFF((I0) + 1)),                              \
              [s2] "s"(xb + IMG_OFF((I0) + 2)),                              \
              [s3] "s"(xb + IMG_OFF((I0) + 3)),                              \
              [s4] "s"(xb + IMG_OFF((I0) + 4)),                              \
              [s5] "s"(xb + IMG_OFF((I0) + 5)));                             \
        f32x2 q0_0 = {0.f, 0.f}, q1_0 = {0.f, 0.f};                          \
        f32x2 q0_1 = {0.f, 0.f}, q1_1 = {0.f, 0.f};                          \
        f32x2 q0_2 = {0.f, 0.f}, q1_2 = {0.f, 0.f};                          \
        f32x2 q0_3 = {0.f, 0.f}, q1_3 = {0.f, 0.f};                          \
        f32x2 q0_4 = {0.f, 0.f}, q1_4 = {0.f, 0.f};                          \
        f32x2 q0_5 = {0.f, 0.f}, q1_5 = {0.f, 0.f};                          \
        if (!compat) {                                                       \
            asm volatile(                                                    \
                "global_load_dwordx2 %[a0], %[vb], %[s0]\n\t"                \
                "global_load_dwordx2 %[b0], %[vb], %[s0] offset:2048\n\t"    \
                "global_load_dwordx2 %[a1], %[vb], %[s1]\n\t"                \
                "global_load_dwordx2 %[b1], %[vb], %[s1] offset:2048\n\t"    \
                "global_load_dwordx2 %[a2], %[vb], %[s2]\n\t"                \
                "global_load_dwordx2 %[b2], %[vb], %[s2] offset:2048\n\t"    \
                "global_load_dwordx2 %[a3], %[vb], %[s3]\n\t"                \
                "global_load_dwordx2 %[b3], %[vb], %[s3] offset:2048\n\t"    \
                "global_load_dwordx2 %[a4], %[vb], %[s4]\n\t"                \
                "global_load_dwordx2 %[b4], %[vb], %[s4] offset:2048\n\t"    \
                "global_load_dwordx2 %[a5], %[vb], %[s5]\n\t"                \
                "global_load_dwordx2 %[b5], %[vb], %[s5] offset:2048"        \
                : [a0] "=&v"(q0_0), [b0] "=&v"(q1_0),                        \
                  [a1] "=&v"(q0_1), [b1] "=&v"(q1_1),                        \
                  [a2] "=&v"(q0_2), [b2] "=&v"(q1_2),                        \
                  [a3] "=&v"(q0_3), [b3] "=&v"(q1_3),                        \
                  [a4] "=&v"(q0_4), [b4] "=&v"(q1_4),                        \
                  [a5] "=&v"(q0_5), [b5] "=&v"(q1_5)                         \
                : [vb] "v"(vbB),                                             \
                  [s0] "s"(xb + IMG_OFF((I0) + 0)),                          \
                  [s1] "s"(xb + IMG_OFF((I0) + 1)),                          \
                  [s2] "s"(xb + IMG_OFF((I0) + 2)),                          \
                  [s3] "s"(xb + IMG_OFF((I0) + 3)),                          \
                  [s4] "s"(xb + IMG_OFF((I0) + 4)),                          \
                  [s5] "s"(xb + IMG_OFF((I0) + 5)));                         \
        }                                                                    \
        asm volatile("s_waitcnt vmcnt(0)" ::: "memory");                     \
        __builtin_amdgcn_sched_barrier(0);                                   \
        EMIT2((I0) + 0, r0_0, r1_0, q0_0, q1_0)                              \
        EMIT2((I0) + 1, r0_1, r1_1, q0_1, q1_1)                              \
        EMIT2((I0) + 2, r0_2, r1_2, q0_2, q1_2)                              \
        EMIT2((I0) + 3, r0_3, r1_3, q0_3, q1_3)                              \
        EMIT2((I0) + 4, r0_4, r1_4, q0_4, q1_4)                              \
        EMIT2((I0) + 5, r0_5, r1_5, q0_5, q1_5)                              \
    }

    ROUND(0)
    ROUND(6)

#undef ROUND
#undef EMIT2
}

extern "C" void kernel_launch(void* const* d_in, const int* in_sizes, int n_in,
                              void* d_out, int out_size, void* d_ws, size_t ws_size,
                              hipStream_t stream) {
    const float* x    = (const float*)d_in[0];
    const float* uv   = (const float*)d_in[1];
    const int*   face = (const int*)d_in[2];
    float*       out  = (float*)d_out;

    // HW/2 pair-threads, 128/block -> 8192 blocks = 8 blocks per equirect
    // row (round-2's proven vertical-strip XCD locality).
    const int grid = (HW / 2) / 128;
    hipLaunchKernelGGL(cube2equirec_kernel, dim3(grid), dim3(128), 0, stream,
                       x, uv, face, out);
}

// Round 7
// 217.242 us; speedup vs baseline: 1.0324x; 1.0324x over previous
//
#include <hip/hip_runtime.h>
#include <stdint.h>

#define EQU_H 1024
#define EQU_W 2048
#define HW (EQU_H * EQU_W)

typedef float f32x4 __attribute__((ext_vector_type(4)));
typedef float f32x2 __attribute__((ext_vector_type(2)));

// byte / float offsets of image i = (e,c)
#define IMG_OFF(i)  ((uint64_t)(((i) / 3) * 18874368u + ((i) % 3) * 1048576u))
#define IMG_FOFF(i) (((i) / 3) * 4718592 + ((i) % 3) * 262144)

// Round-13: rounds 2/4/6 all gather 402 MB (192 B/px) and all land at
// 90-100us at ~4.4-4.5 TB/s regardless of instruction count (48 vs 24),
// occupancy (73% vs 37%), line splits, or HBM traffic (55 vs 139 MB).
// => limiter is the vector-memory return path (~8 B/lane-slot/cy/CU).
// Per-pixel windows have an irreducible 24 slots/px -> ~90us floor.
// Fix: route bytes off that path. Blocks own 32x16-px tiles; when the
// tile's cube footprint is single-face and fits a 64x32 texel bbox
// (face interiors, ~75% of tiles), stage the bbox with COALESCED
// dwordx4 (~120 B/px) and gather from LDS (separate, much faster pipe).
// Other tiles take the exact round-6 body as a block-uniform fallback.
// Tile grid 64 wide -> vertical neighbors bid+-64 = same XCD (mod 8):
// round-2's vertical-strip L2 locality preserved.
__device__ __forceinline__ int wave_min(int v) {
#pragma unroll
    for (int o = 32; o; o >>= 1) v = min(v, __shfl_xor(v, o));
    return v;
}
__device__ __forceinline__ int wave_max(int v) {
#pragma unroll
    for (int o = 32; o; o >>= 1) v = max(v, __shfl_xor(v, o));
    return v;
}

__global__ __launch_bounds__(256, 1) void cube2equirec_kernel(
    const float* __restrict__ x,
    const float* __restrict__ uv,
    const int*   __restrict__ face,
    float*       __restrict__ out)
{
    __shared__ float slds[3][2048];   // 3 images x 32 rows x 64 cols = 24 KB
    __shared__ int   sred[24];        // 4 waves x 6 reduce slots

    const int tx = blockIdx.x & 63;   // 64 tiles across (32 px each)
    const int ty = blockIdx.x >> 6;   // 64 tiles down (16 rows each)
    const int pr = threadIdx.x & 15;  // pair column within tile
    const int rw = threadIdx.x >> 4;  // row within tile
    const int w  = tx * 32 + pr * 2;
    const int h  = ty * 16 + rw;
    const int idx  = h * EQU_W + w;   // left pixel of the pair
    const int pidx = idx >> 1;

    const f32x4 uv4 = ((const f32x4*)uv)[pidx];   // uA vA uB vB
    const int2  fpr = ((const int2*)face)[pidx];
    const float uA = uv4.x, vA = uv4.y, uB = uv4.z, vB = uv4.w;
    const int   fA = fpr.x, fB = fpr.y;

    int x0A = (int)floorf(uA), y0A = (int)floorf(vA);
    int x0B = (int)floorf(uB), y0B = (int)floorf(vB);
    x0A = min(max(x0A, 0), 510); y0A = min(max(y0A, 0), 510);
    x0B = min(max(x0B, 0), 510); y0B = min(max(y0B, 0), 510);
    const float wxA = uA - (float)x0A, wyA = vA - (float)y0A;
    const float wxB = uB - (float)x0B, wyB = vB - (float)y0B;

    // ---- block-wide footprint reduction ----
    int fmn = min(fA, fB),   fmx = max(fA, fB);
    int xmn = min(x0A, x0B), xmx = max(x0A, x0B);
    int ymn = min(y0A, y0B), ymx = max(y0A, y0B);
    fmn = wave_min(fmn); fmx = wave_max(fmx);
    xmn = wave_min(xmn); xmx = wave_max(xmx);
    ymn = wave_min(ymn); ymx = wave_max(ymx);
    const int wid = threadIdx.x >> 6, lane = threadIdx.x & 63;
    if (lane == 0) {
        int* p = &sred[wid * 6];
        p[0] = fmn; p[1] = fmx; p[2] = xmn; p[3] = xmx; p[4] = ymn; p[5] = ymx;
    }
    __syncthreads();
#pragma unroll
    for (int ww = 0; ww < 4; ++ww) {
        const int* p = &sred[ww * 6];
        fmn = min(fmn, p[0]); fmx = max(fmx, p[1]);
        xmn = min(xmn, p[2]); xmx = max(xmx, p[3]);
        ymn = min(ymn, p[4]); ymx = max(ymx, p[5]);
    }

    const int  xs     = min(xmn & ~3, 448);          // aligned, 64 cols in-bounds
    const bool staged = (fmn == fmx) && ((xmx + 1 - xs) <= 63)
                                     && ((ymx - ymn) <= 29);
    const uint64_t xb = (uint64_t)x;

    if (staged) {
        // ===================== staged path =====================
        const int R  = ymx + 2 - ymn;                // rows to stage, <= 31
        const int nu = R << 4;                       // 16 dwordx4-units per row
        const float w00A = (1.f - wxA) * (1.f - wyA), w01A = wxA * (1.f - wyA);
        const float w10A = (1.f - wxA) * wyA,         w11A = wxA * wyA;
        const float w00B = (1.f - wxB) * (1.f - wyB), w01B = wxB * (1.f - wyB);
        const float w10B = (1.f - wxB) * wyB,         w11B = wxB * wyB;
        const int lA = ((y0A - ymn) << 6) + (x0A - xs);
        const int lB = ((y0B - ymn) << 6) + (x0B - xs);
        const int fbase = fmn * 786432;              // face offset in floats

#pragma unroll
        for (int k = 0; k < 4; ++k) {
            // stage 3 images (coalesced dwordx4)
#pragma unroll
            for (int r = 0; r < 3; ++r) {
                const float* src = x + IMG_FOFF(k * 3 + r) + fbase;
                int u = threadIdx.x;
                if (u < nu) {
                    const int row = u >> 4, c4 = (u & 15) << 2;
                    *((f32x4*)&slds[r][(row << 6) + c4]) =
                        *(const f32x4*)(src + (ymn + row) * 512 + xs + c4);
                }
                u += 256;
                if (u < nu) {
                    const int row = u >> 4, c4 = (u & 15) << 2;
                    *((f32x4*)&slds[r][(row << 6) + c4]) =
                        *(const f32x4*)(src + (ymn + row) * 512 + xs + c4);
                }
            }
            __syncthreads();
#pragma unroll
            for (int r = 0; r < 3; ++r) {
                const int i = k * 3 + r;
                const float* L = slds[r];
                const float a00 = L[lA], a01 = L[lA + 1];
                const float a10 = L[lA + 64], a11 = L[lA + 65];
                const float b00 = L[lB], b01 = L[lB + 1];
                const float b10 = L[lB + 64], b11 = L[lB + 65];
                f32x2 st;
                st.x = a00 * w00A + a01 * w01A + a10 * w10A + a11 * w11A;
                st.y = b00 * w00B + b01 * w01B + b10 * w10B + b11 * w11B;
                __builtin_nontemporal_store(st, (f32x2*)(out + (size_t)i * HW) + pidx);
            }
            __syncthreads();
        }
        return;
    }

    // ===================== fallback: exact round-6 body =====================
    const int  xmw    = min(x0A, x0B);
    const bool compat = (fA == fB) && (y0A == y0B)
                     && ((max(x0A, x0B) - xmw) <= 2);
    const int xm  = min(compat ? xmw : x0A, 508);
    const int oAw = x0A - xm;
    const int oBw = min(max(x0B - xm, 0), 2);

    const uint32_t vbW = (uint32_t)(fA * 3145728 + y0A * 2048 + xm * 4);
    const uint32_t vbB = (uint32_t)(fB * 3145728 + y0B * 2048 + x0B * 4);

    const float aL = 1.f - wxA, aR = wxA;
    const float bL = 1.f - wxB, bR = wxB;
    f32x4 WA, WB;
    WA.x = (oAw == 0) ? aL : 0.f;
    WA.y = (oAw == 0) ? aR : ((oAw == 1) ? aL : 0.f);
    WA.z = (oAw == 2) ? aL : ((oAw == 1) ? aR : 0.f);
    WA.w = (oAw == 2) ? aR : 0.f;
    WB.x = (oBw == 0) ? bL : 0.f;
    WB.y = (oBw == 0) ? bR : ((oBw == 1) ? bL : 0.f);
    WB.z = (oBw == 2) ? bL : ((oBw == 1) ? bR : 0.f);
    WB.w = (oBw == 2) ? bR : 0.f;
    const f32x4 WA0 = WA * (1.f - wyA), WA1 = WA * wyA;
    const f32x4 WB0 = WB * (1.f - wyB), WB1 = WB * wyB;
    const float c00 = bL * (1.f - wyB), c01 = bR * (1.f - wyB);
    const float c10 = bL * wyB,         c11 = bR * wyB;

#define EMIT2(i, R0, R1, Q0, Q1)                                             \
    {                                                                        \
        const float ovA = R0.x * WA0.x + R0.y * WA0.y + R0.z * WA0.z         \
                        + R0.w * WA0.w + R1.x * WA1.x + R1.y * WA1.y         \
                        + R1.z * WA1.z + R1.w * WA1.w;                       \
        const float oBw2 = R0.x * WB0.x + R0.y * WB0.y + R0.z * WB0.z        \
                        + R0.w * WB0.w + R1.x * WB1.x + R1.y * WB1.y         \
                        + R1.z * WB1.z + R1.w * WB1.w;                       \
        const float oBf = Q0.x * c00 + Q0.y * c01 + Q1.x * c10 + Q1.y * c11; \
        f32x2 st;                                                            \
        st.x = ovA;                                                          \
        st.y = compat ? oBw2 : oBf;                                          \
        __builtin_nontemporal_store(st, (f32x2*)(out + (size_t)(i) * HW) + pidx); \
    }

#define ROUND(I0)                                                            \
    {                                                                        \
        f32x4 r0_0, r1_0, r0_1, r1_1, r0_2, r1_2,                            \
              r0_3, r1_3, r0_4, r1_4, r0_5, r1_5;                            \
        asm volatile(                                                        \
            "global_load_dwordx4 %[a0], %[vb], %[s0]\n\t"                    \
            "global_load_dwordx4 %[b0], %[vb], %[s0] offset:2048\n\t"        \
            "global_load_dwordx4 %[a1], %[vb], %[s1]\n\t"                    \
            "global_load_dwordx4 %[b1], %[vb], %[s1] offset:2048\n\t"        \
            "global_load_dwordx4 %[a2], %[vb], %[s2]\n\t"                    \
            "global_load_dwordx4 %[b2], %[vb], %[s2] offset:2048\n\t"        \
            "global_load_dwordx4 %[a3], %[vb], %[s3]\n\t"                    \
            "global_load_dwordx4 %[b3], %[vb], %[s3] offset:2048\n\t"        \
            "global_load_dwordx4 %[a4], %[vb], %[s4]\n\t"                    \
            "global_load_dwordx4 %[b4], %[vb], %[s4] offset:2048\n\t"        \
            "global_load_dwordx4 %[a5], %[vb], %[s5]\n\t"                    \
            "global_load_dwordx4 %[b5], %[vb], %[s5] offset:2048"            \
            : [a0] "=&v"(r0_0), [b0] "=&v"(r1_0),                            \
              [a1] "=&v"(r0_1), [b1] "=&v"(r1_1),                            \
              [a2] "=&v"(r0_2), [b2] "=&v"(r1_2),                            \
              [a3] "=&v"(r0_3), [b3] "=&v"(r1_3),                            \
              [a4] "=&v"(r0_4), [b4] "=&v"(r1_4),                            \
              [a5] "=&v"(r0_5), [b5] "=&v"(r1_5)                             \
            : [vb] "v"(vbW),                                                 \
              [s0] "s"(xb + IMG_OFF((I0) + 0)),                              \
              [s1] "s"(xb + IMG_OFF((I0) + 1)),                              \
              [s2] "s"(xb + IMG_OFF((I0) + 2)),                              \
              [s3] "s"(xb + IMG_OFF((I0) + 3)),                              \
              [s4] "s"(xb + IMG_OFF((I0) + 4)),                              \
              [s5] "s"(xb + IMG_OFF((I0) + 5)));                             \
        f32x2 q0_0 = {0.f, 0.f}, q1_0 = {0.f, 0.f};                          \
        f32x2 q0_1 = {0.f, 0.f}, q1_1 = {0.f, 0.f};                          \
        f32x2 q0_2 = {0.f, 0.f}, q1_2 = {0.f, 0.f};                          \
        f32x2 q0_3 = {0.f, 0.f}, q1_3 = {0.f, 0.f};                          \
        f32x2 q0_4 = {0.f, 0.f}, q1_4 = {0.f, 0.f};                          \
        f32x2 q0_5 = {0.f, 0.f}, q1_5 = {0.f, 0.f};                          \
        if (!compat) {                                                       \
            asm volatile(                                                    \
                "global_load_dwordx2 %[a0], %[vb], %[s0]\n\t"                \
                "global_load_dwordx2 %[b0], %[vb], %[s0] offset:2048\n\t"    \
                "global_load_dwordx2 %[a1], %[vb], %[s1]\n\t"                \
                "global_load_dwordx2 %[b1], %[vb], %[s1] offset:2048\n\t"    \
                "global_load_dwordx2 %[a2], %[vb], %[s2]\n\t"                \
                "global_load_dwordx2 %[b2], %[vb], %[s2] offset:2048\n\t"    \
                "global_load_dwordx2 %[a3], %[vb], %[s3]\n\t"                \
                "global_load_dwordx2 %[b3], %[vb], %[s3] offset:2048\n\t"    \
                "global_load_dwordx2 %[a4], %[vb], %[s4]\n\t"                \
                "global_load_dwordx2 %[b4], %[vb], %[s4] offset:2048\n\t"    \
                "global_load_dwordx2 %[a5], %[vb], %[s5]\n\t"                \
                "global_load_dwordx2 %[b5], %[vb], %[s5] offset:2048"        \
                : [a0] "=&v"(q0_0), [b0] "=&v"(q1_0),                        \
                  [a1] "=&v"(q0_1), [b1] "=&v"(q1_1),                        \
                  [a2] "=&v"(q0_2), [b2] "=&v"(q1_2),                        \
                  [a3] "=&v"(q0_3), [b3] "=&v"(q1_3),                        \
                  [a4] "=&v"(q0_4), [b4] "=&v"(q1_4),                        \
                  [a5] "=&v"(q0_5), [b5] "=&v"(q1_5)                         \
                : [vb] "v"(vbB),                                             \
                  [s0] "s"(xb + IMG_OFF((I0) + 0)),                          \
                  [s1] "s"(xb + IMG_OFF((I0) + 1)),                          \
                  [s2] "s"(xb + IMG_OFF((I0) + 2)),                          \
                  [s3] "s"(xb + IMG_OFF((I0) + 3)),                          \
                  [s4] "s"(xb + IMG_OFF((I0) + 4)),                          \
                  [s5] "s"(xb + IMG_OFF((I0) + 5)));                         \
        }                                                                    \
        asm volatile("s_waitcnt vmcnt(0)" ::: "memory");                     \
        __builtin_amdgcn_sched_barrier(0);                                   \
        EMIT2((I0) + 0, r0_0, r1_0, q0_0, q1_0)                              \
        EMIT2((I0) + 1, r0_1, r1_1, q0_1, q1_1)                              \
        EMIT2((I0) + 2, r0_2, r1_2, q0_2, q1_2)                              \
        EMIT2((I0) + 3, r0_3, r1_3, q0_3, q1_3)                              \
        EMIT2((I0) + 4, r0_4, r1_4, q0_4, q1_4)                              \
        EMIT2((I0) + 5, r0_5, r1_5, q0_5, q1_5)                              \
    }

    ROUND(0)
    ROUND(6)

#undef ROUND
#undef EMIT2
}

extern "C" void kernel_launch(void* const* d_in, const int* in_sizes, int n_in,
                              void* d_out, int out_size, void* d_ws, size_t ws_size,
                              hipStream_t stream) {
    const float* x    = (const float*)d_in[0];
    const float* uv   = (const float*)d_in[1];
    const int*   face = (const int*)d_in[2];
    float*       out  = (float*)d_out;

    // 64 x 64 tiles of 32x16 px; vertical tile neighbors are bid +- 64
    // (same XCD mod 8) -> round-2's vertical-strip L2 locality.
    const int grid = 64 * 64;  // 4096 blocks
    hipLaunchKernelGGL(cube2equirec_kernel, dim3(grid), dim3(256), 0, stream,
                       x, uv, face, out);
}

// Round 8
// 214.303 us; speedup vs baseline: 1.0465x; 1.0137x over previous
//
#include <hip/hip_runtime.h>
#include <stdint.h>

#define EQU_H 1024
#define EQU_W 2048
#define HW (EQU_H * EQU_W)

typedef float f32x4 __attribute__((ext_vector_type(4)));
typedef float f32x2 __attribute__((ext_vector_type(2)));

// byte / float offsets of image i = (e,c)
#define IMG_OFF(i)  ((uint64_t)(((i) / 3) * 18874368u + ((i) % 3) * 1048576u))
#define IMG_FOFF(i) (((i) / 3) * 4718592 + ((i) % 3) * 262144)

// Round-14 model (fits rounds 0-7): time == total vmem REQUESTED bytes
// at ~5.5-6 TB/s (copy ceiling), independent of instruction count,
// occupancy, line splits, or cache residency. 250 B/px (192 gather + 58
// IO) -> 95us. Only byte reduction wins. Staging dedupes taps: footprint
// ~1.2-2.5 texels/px vs 8 taps/px.
// v2 of the hybrid: (1) ADAPTIVE tight windows - per-block bbox C x R
// (C mult-of-4), staged iff C*R <= 1600 texels: staged bytes ~90-100
// B/px and admits face-edge + radial pole tiles that R7's fixed 64-col
// test rejected (phi ~0.5 -> ~0.7). (2) column-major tile order:
// horizontal neighbors (shared cube rows / window overlap) are
// delta-bid=64 == same XCD (64%8==0) -> over-fetch is L2-reused (R7's
// FETCH blowup 55->128MB came from neighbors on different XCDs).
// Fallback = exact round-6 pair-window body (proven).
__device__ __forceinline__ int wave_min(int v) {
#pragma unroll
    for (int o = 32; o; o >>= 1) v = min(v, __shfl_xor(v, o));
    return v;
}
__device__ __forceinline__ int wave_max(int v) {
#pragma unroll
    for (int o = 32; o; o >>= 1) v = max(v, __shfl_xor(v, o));
    return v;
}

__global__ __launch_bounds__(256, 1) void cube2equirec_kernel(
    const float* __restrict__ x,
    const float* __restrict__ uv,
    const int*   __restrict__ face,
    float*       __restrict__ out)
{
    __shared__ float slds[3][1600];   // 3 images x <=1600 texels = 19.2 KB
    __shared__ int   sred[24];        // 4 waves x 6 reduce slots

    // column-major tile order: ty in low bits -> horizontal tile
    // neighbors are bid+-64 (same XCD mod 8), co-resident in time.
    const int ty = blockIdx.x & 63;   // 64 tile-rows (16 px each)
    const int tx = blockIdx.x >> 6;   // 64 tile-cols (32 px each)
    const int pr = threadIdx.x & 15;  // pair column within tile
    const int rw = threadIdx.x >> 4;  // row within tile
    const int w  = tx * 32 + pr * 2;
    const int h  = ty * 16 + rw;
    const int pidx = (h * EQU_W + w) >> 1;

    const f32x4 uv4 = ((const f32x4*)uv)[pidx];   // uA vA uB vB
    const int2  fpr = ((const int2*)face)[pidx];
    const float uA = uv4.x, vA = uv4.y, uB = uv4.z, vB = uv4.w;
    const int   fA = fpr.x, fB = fpr.y;

    int x0A = (int)floorf(uA), y0A = (int)floorf(vA);
    int x0B = (int)floorf(uB), y0B = (int)floorf(vB);
    x0A = min(max(x0A, 0), 510); y0A = min(max(y0A, 0), 510);
    x0B = min(max(x0B, 0), 510); y0B = min(max(y0B, 0), 510);
    const float wxA = uA - (float)x0A, wyA = vA - (float)y0A;
    const float wxB = uB - (float)x0B, wyB = vB - (float)y0B;

    // ---- block-wide footprint reduction ----
    int fmn = min(fA, fB),   fmx = max(fA, fB);
    int xmn = min(x0A, x0B), xmx = max(x0A, x0B);
    int ymn = min(y0A, y0B), ymx = max(y0A, y0B);
    fmn = wave_min(fmn); fmx = wave_max(fmx);
    xmn = wave_min(xmn); xmx = wave_max(xmx);
    ymn = wave_min(ymn); ymx = wave_max(ymx);
    const int wid = threadIdx.x >> 6, lane = threadIdx.x & 63;
    if (lane == 0) {
        int* p = &sred[wid * 6];
        p[0] = fmn; p[1] = fmx; p[2] = xmn; p[3] = xmx; p[4] = ymn; p[5] = ymx;
    }
    __syncthreads();
#pragma unroll
    for (int ww = 0; ww < 4; ++ww) {
        const int* p = &sred[ww * 6];
        fmn = min(fmn, p[0]); fmx = max(fmx, p[1]);
        xmn = min(xmn, p[2]); xmx = max(xmx, p[3]);
        ymn = min(ymn, p[4]); ymx = max(ymx, p[5]);
    }

    // ---- adaptive window: C cols (mult of 4) x R rows, tight bbox ----
    const int xs = xmn & ~3;                     // 4-aligned start col
    const int R  = ymx + 2 - ymn;                // rows incl. +1 tap row
    int C = ((xmx + 2 - xs) + 3) & ~3;           // cols incl. +1 tap col
    C = min(C, 512 - xs);                        // stay inside the row
    const int  U      = C >> 2;                  // f32x4 units per row
    const bool staged = (fmn == fmx) && (U * R <= 400);  // <=1600 texels
    const uint64_t xb = (uint64_t)x;

    if (staged) {                                // block-uniform branch
        // ===================== staged path =====================
        const int UR = U * R;
        const int fbase = fmn * 786432;          // face offset in floats
        const int u0 = threadIdx.x, u1 = threadIdx.x + 256;
        const int r0 = u0 / U, c0 = u0 - r0 * U;
        const int r1 = u1 / U, c1 = u1 - r1 * U;
        const bool g0 = u0 < UR, g1 = u1 < UR;
        const int go0 = (ymn + r0) * 512 + xs + (c0 << 2);
        const int go1 = (ymn + r1) * 512 + xs + (c1 << 2);
        const int lo0 = r0 * C + (c0 << 2);
        const int lo1 = r1 * C + (c1 << 2);
        const int lA = (y0A - ymn) * C + (x0A - xs);
        const int lB = (y0B - ymn) * C + (x0B - xs);

        const float w00A = (1.f - wxA) * (1.f - wyA), w01A = wxA * (1.f - wyA);
        const float w10A = (1.f - wxA) * wyA,         w11A = wxA * wyA;
        const float w00B = (1.f - wxB) * (1.f - wyB), w01B = wxB * (1.f - wyB);
        const float w10B = (1.f - wxB) * wyB,         w11B = wxB * wyB;

#pragma unroll
        for (int k = 0; k < 4; ++k) {
#pragma unroll
            for (int r = 0; r < 3; ++r) {
                const float* src = x + IMG_FOFF(k * 3 + r) + fbase;
                if (g0) *((f32x4*)&slds[r][lo0]) = *(const f32x4*)(src + go0);
                if (g1) *((f32x4*)&slds[r][lo1]) = *(const f32x4*)(src + go1);
            }
            __syncthreads();
#pragma unroll
            for (int r = 0; r < 3; ++r) {
                const int i = k * 3 + r;
                const float* L = slds[r];
                const float a00 = L[lA], a01 = L[lA + 1];
                const float a10 = L[lA + C], a11 = L[lA + C + 1];
                const float b00 = L[lB], b01 = L[lB + 1];
                const float b10 = L[lB + C], b11 = L[lB + C + 1];
                f32x2 st;
                st.x = a00 * w00A + a01 * w01A + a10 * w10A + a11 * w11A;
                st.y = b00 * w00B + b01 * w01B + b10 * w10B + b11 * w11B;
                __builtin_nontemporal_store(st, (f32x2*)(out + (size_t)i * HW) + pidx);
            }
            __syncthreads();
        }
        return;
    }

    // ===================== fallback: exact round-6 body =====================
    const int  xmw    = min(x0A, x0B);
    const bool compat = (fA == fB) && (y0A == y0B)
                     && ((max(x0A, x0B) - xmw) <= 2);
    const int xm  = min(compat ? xmw : x0A, 508);
    const int oAw = x0A - xm;
    const int oBw = min(max(x0B - xm, 0), 2);

    const uint32_t vbW = (uint32_t)(fA * 3145728 + y0A * 2048 + xm * 4);
    const uint32_t vbB = (uint32_t)(fB * 3145728 + y0B * 2048 + x0B * 4);

    const float aL = 1.f - wxA, aR = wxA;
    const float bL = 1.f - wxB, bR = wxB;
    f32x4 WA, WB;
    WA.x = (oAw == 0) ? aL : 0.f;
    WA.y = (oAw == 0) ? aR : ((oAw == 1) ? aL : 0.f);
    WA.z = (oAw == 2) ? aL : ((oAw == 1) ? aR : 0.f);
    WA.w = (oAw == 2) ? aR : 0.f;
    WB.x = (oBw == 0) ? bL : 0.f;
    WB.y = (oBw == 0) ? bR : ((oBw == 1) ? bL : 0.f);
    WB.z = (oBw == 2) ? bL : ((oBw == 1) ? bR : 0.f);
    WB.w = (oBw == 2) ? bR : 0.f;
    const f32x4 WA0 = WA * (1.f - wyA), WA1 = WA * wyA;
    const f32x4 WB0 = WB * (1.f - wyB), WB1 = WB * wyB;
    const float c00 = bL * (1.f - wyB), c01 = bR * (1.f - wyB);
    const float c10 = bL * wyB,         c11 = bR * wyB;

#define EMIT2(i, R0, R1, Q0, Q1)                                             \
    {                                                                        \
        const float ovA = R0.x * WA0.x + R0.y * WA0.y + R0.z * WA0.z         \
                        + R0.w * WA0.w + R1.x * WA1.x + R1.y * WA1.y         \
                        + R1.z * WA1.z + R1.w * WA1.w;                       \
        const float oBw2 = R0.x * WB0.x + R0.y * WB0.y + R0.z * WB0.z        \
                        + R0.w * WB0.w + R1.x * WB1.x + R1.y * WB1.y         \
                        + R1.z * WB1.z + R1.w * WB1.w;                       \
        const float oBf = Q0.x * c00 + Q0.y * c01 + Q1.x * c10 + Q1.y * c11; \
        f32x2 st;                                                            \
        st.x = ovA;                                                          \
        st.y = compat ? oBw2 : oBf;                                          \
        __builtin_nontemporal_store(st, (f32x2*)(out + (size_t)(i) * HW) + pidx); \
    }

#define ROUND(I0)                                                            \
    {                                                                        \
        f32x4 r0_0, r1_0, r0_1, r1_1, r0_2, r1_2,                            \
              r0_3, r1_3, r0_4, r1_4, r0_5, r1_5;                            \
        asm volatile(                                                        \
            "global_load_dwordx4 %[a0], %[vb], %[s0]\n\t"                    \
            "global_load_dwordx4 %[b0], %[vb], %[s0] offset:2048\n\t"        \
            "global_load_dwordx4 %[a1], %[vb], %[s1]\n\t"                    \
            "global_load_dwordx4 %[b1], %[vb], %[s1] offset:2048\n\t"        \
            "global_load_dwordx4 %[a2], %[vb], %[s2]\n\t"                    \
            "global_load_dwordx4 %[b2], %[vb], %[s2] offset:2048\n\t"        \
            "global_load_dwordx4 %[a3], %[vb], %[s3]\n\t"                    \
            "global_load_dwordx4 %[b3], %[vb], %[s3] offset:2048\n\t"        \
            "global_load_dwordx4 %[a4], %[vb], %[s4]\n\t"                    \
            "global_load_dwordx4 %[b4], %[vb], %[s4] offset:2048\n\t"        \
            "global_load_dwordx4 %[a5], %[vb], %[s5]\n\t"                    \
            "global_load_dwordx4 %[b5], %[vb], %[s5] offset:2048"            \
            : [a0] "=&v"(r0_0), [b0] "=&v"(r1_0),                            \
              [a1] "=&v"(r0_1), [b1] "=&v"(r1_1),                            \
              [a2] "=&v"(r0_2), [b2] "=&v"(r1_2),                            \
              [a3] "=&v"(r0_3), [b3] "=&v"(r1_3),                            \
              [a4] "=&v"(r0_4), [b4] "=&v"(r1_4),                            \
              [a5] "=&v"(r0_5), [b5] "=&v"(r1_5)                             \
            : [vb] "v"(vbW),                                                 \
              [s0] "s"(xb + IMG_OFF((I0) + 0)),                              \
              [s1] "s"(xb + IMG_OFF((I0) + 1)),                              \
              [s2] "s"(xb + IMG_OFF((I0) + 2)),                              \
              [s3] "s"(xb + IMG_OFF((I0) + 3)),                              \
              [s4] "s"(xb + IMG_OFF((I0) + 4)),                              \
              [s5] "s"(xb + IMG_OFF((I0) + 5)));                             \
        f32x2 q0_0 = {0.f, 0.f}, q1_0 = {0.f, 0.f};                          \
        f32x2 q0_1 = {0.f, 0.f}, q1_1 = {0.f, 0.f};                          \
        f32x2 q0_2 = {0.f, 0.f}, q1_2 = {0.f, 0.f};                          \
        f32x2 q0_3 = {0.f, 0.f}, q1_3 = {0.f, 0.f};                          \
        f32x2 q0_4 = {0.f, 0.f}, q1_4 = {0.f, 0.f};                          \
        f32x2 q0_5 = {0.f, 0.f}, q1_5 = {0.f, 0.f};                          \
        if (!compat) {                                                       \
            asm volatile(                                                    \
                "global_load_dwordx2 %[a0], %[vb], %[s0]\n\t"                \
                "global_load_dwordx2 %[b0], %[vb], %[s0] offset:2048\n\t"    \
                "global_load_dwordx2 %[a1], %[vb], %[s1]\n\t"                \
                "global_load_dwordx2 %[b1], %[vb], %[s1] offset:2048\n\t"    \
                "global_load_dwordx2 %[a2], %[vb], %[s2]\n\t"                \
                "global_load_dwordx2 %[b2], %[vb], %[s2] offset:2048\n\t"    \
                "global_load_dwordx2 %[a3], %[vb], %[s3]\n\t"                \
                "global_load_dwordx2 %[b3], %[vb], %[s3] offset:2048\n\t"    \
                "global_load_dwordx2 %[a4], %[vb], %[s4]\n\t"                \
                "global_load_dwordx2 %[b4], %[vb], %[s4] offset:2048\n\t"    \
                "global_load_dwordx2 %[a5], %[vb], %[s5]\n\t"                \
                "global_load_dwordx2 %[b5], %[vb], %[s5] offset:2048"        \
                : [a0] "=&v"(q0_0), [b0] "=&v"(q1_0),                        \
                  [a1] "=&v"(q0_1), [b1] "=&v"(q1_1),                        \
                  [a2] "=&v"(q0_2), [b2] "=&v"(q1_2),                        \
                  [a3] "=&v"(q0_3), [b3] "=&v"(q1_3),                        \
                  [a4] "=&v"(q0_4), [b4] "=&v"(q1_4),                        \
                  [a5] "=&v"(q0_5), [b5] "=&v"(q1_5)                         \
                : [vb] "v"(vbB),                                             \
                  [s0] "s"(xb + IMG_OFF((I0) + 0)),                          \
                  [s1] "s"(xb + IMG_OFF((I0) + 1)),                          \
                  [s2] "s"(xb + IMG_OFF((I0) + 2)),                          \
                  [s3] "s"(xb + IMG_OFF((I0) + 3)),                          \
                  [s4] "s"(xb + IMG_OFF((I0) + 4)),                          \
                  [s5] "s"(xb + IMG_OFF((I0) + 5)));                         \
        }                                                                    \
        asm volatile("s_waitcnt vmcnt(0)" ::: "memory");                     \
        __builtin_amdgcn_sched_barrier(0);                                   \
        EMIT2((I0) + 0, r0_0, r1_0, q0_0, q1_0)                              \
        EMIT2((I0) + 1, r0_1, r1_1, q0_1, q1_1)                              \
        EMIT2((I0) + 2, r0_2, r1_2, q0_2, q1_2)                              \
        EMIT2((I0) + 3, r0_3, r1_3, q0_3, q1_3)                              \
        EMIT2((I0) + 4, r0_4, r1_4, q0_4, q1_4)                              \
        EMIT2((I0) + 5, r0_5, r1_5, q0_5, q1_5)                              \
    }

    ROUND(0)
    ROUND(6)

#undef ROUND
#undef EMIT2
}

extern "C" void kernel_launch(void* const* d_in, const int* in_sizes, int n_in,
                              void* d_out, int out_size, void* d_ws, size_t ws_size,
                              hipStream_t stream) {
    const float* x    = (const float*)d_in[0];
    const float* uv   = (const float*)d_in[1];
    const int*   face = (const int*)d_in[2];
    float*       out  = (float*)d_out;

    const int grid = 64 * 64;  // 4096 tiles of 32x16 px, column-major order
    hipLaunchKernelGGL(cube2equirec_kernel, dim3(grid), dim3(256), 0, stream,
                       x, uv, face, out);
}

// Round 9
// 195.079 us; speedup vs baseline: 1.1497x; 1.0985x over previous
//
#include <hip/hip_runtime.h>
#include <stdint.h>

#define EQU_H 1024
#define EQU_W 2048
#define HW (EQU_H * EQU_W)

typedef float f32x4 __attribute__((ext_vector_type(4)));
typedef float f32x2 __attribute__((ext_vector_type(2)));

// byte / float offsets of image i = (e,c)
#define IMG_OFF(i)  ((uint64_t)(((i) / 3) * 18874368u + ((i) % 3) * 1048576u))
#define IMG_FOFF(i) (((i) / 3) * 4718592 + ((i) % 3) * 262144)

// Round-15: R8 confirmed column-major XCD order (FETCH 128->80MB) but dur
// stuck at 90.5 vs ~61us of requested vmem-slot time. Gap isolated: the
// staged path exposes ~600cy of staging latency per k-round on the block
// critical path (loads issued after the barrier, consumed immediately by
// the LDS write; only ~2.6 blocks/CU resident to overlap). Fix = T14
// async-STAGE split: preload round-0 window to regs; per round write LDS
// from regs, barrier, ISSUE k+1 loads (hidden under compute+barrier),
// compute, barrier. sched_barrier(0) pins the issue above the compute
// (round-0 lesson: compiler sinks batched loads to their use).
// Also: admission threshold 400->512 units (C*R<=2048, LDS 24KB, 6
// blocks/CU) to capture the 45-55deg gradient bands. Fallback = exact
// round-6 pair-window body (proven).
__device__ __forceinline__ int wave_min(int v) {
#pragma unroll
    for (int o = 32; o; o >>= 1) v = min(v, __shfl_xor(v, o));
    return v;
}
__device__ __forceinline__ int wave_max(int v) {
#pragma unroll
    for (int o = 32; o; o >>= 1) v = max(v, __shfl_xor(v, o));
    return v;
}

__global__ __launch_bounds__(256, 1) void cube2equirec_kernel(
    const float* __restrict__ x,
    const float* __restrict__ uv,
    const int*   __restrict__ face,
    float*       __restrict__ out)
{
    __shared__ float slds[3][2048];   // 3 images x <=2048 texels = 24 KB
    __shared__ int   sred[24];        // 4 waves x 6 reduce slots

    // column-major tile order: horizontal tile neighbors are bid+-64
    // (same XCD mod 8), co-resident -> window over-fetch is L2-reused.
    const int ty = blockIdx.x & 63;   // 64 tile-rows (16 px each)
    const int tx = blockIdx.x >> 6;   // 64 tile-cols (32 px each)
    const int pr = threadIdx.x & 15;  // pair column within tile
    const int rw = threadIdx.x >> 4;  // row within tile
    const int w  = tx * 32 + pr * 2;
    const int h  = ty * 16 + rw;
    const int pidx = (h * EQU_W + w) >> 1;

    const f32x4 uv4 = ((const f32x4*)uv)[pidx];   // uA vA uB vB
    const int2  fpr = ((const int2*)face)[pidx];
    const float uA = uv4.x, vA = uv4.y, uB = uv4.z, vB = uv4.w;
    const int   fA = fpr.x, fB = fpr.y;

    int x0A = (int)floorf(uA), y0A = (int)floorf(vA);
    int x0B = (int)floorf(uB), y0B = (int)floorf(vB);
    x0A = min(max(x0A, 0), 510); y0A = min(max(y0A, 0), 510);
    x0B = min(max(x0B, 0), 510); y0B = min(max(y0B, 0), 510);
    const float wxA = uA - (float)x0A, wyA = vA - (float)y0A;
    const float wxB = uB - (float)x0B, wyB = vB - (float)y0B;

    // ---- block-wide footprint reduction ----
    int fmn = min(fA, fB),   fmx = max(fA, fB);
    int xmn = min(x0A, x0B), xmx = max(x0A, x0B);
    int ymn = min(y0A, y0B), ymx = max(y0A, y0B);
    fmn = wave_min(fmn); fmx = wave_max(fmx);
    xmn = wave_min(xmn); xmx = wave_max(xmx);
    ymn = wave_min(ymn); ymx = wave_max(ymx);
    const int wid = threadIdx.x >> 6, lane = threadIdx.x & 63;
    if (lane == 0) {
        int* p = &sred[wid * 6];
        p[0] = fmn; p[1] = fmx; p[2] = xmn; p[3] = xmx; p[4] = ymn; p[5] = ymx;
    }
    __syncthreads();
#pragma unroll
    for (int ww = 0; ww < 4; ++ww) {
        const int* p = &sred[ww * 6];
        fmn = min(fmn, p[0]); fmx = max(fmx, p[1]);
        xmn = min(xmn, p[2]); xmx = max(xmx, p[3]);
        ymn = min(ymn, p[4]); ymx = max(ymx, p[5]);
    }

    // ---- adaptive window: C cols (mult of 4) x R rows, tight bbox ----
    const int xs = xmn & ~3;                     // 4-aligned start col
    const int R  = ymx + 2 - ymn;                // rows incl. +1 tap row
    int C = ((xmx + 2 - xs) + 3) & ~3;           // cols incl. +1 tap col
    C = min(C, 512 - xs);                        // stay inside the row
    const int  U      = C >> 2;                  // f32x4 units per row
    const bool staged = (fmn == fmx) && (U * R <= 512);  // <=2048 texels
    const uint64_t xb = (uint64_t)x;

    if (staged) {                                // block-uniform branch
        // ===================== staged path (T14 pipelined) ==============
        const int UR = U * R;
        const int fbase = fmn * 786432;          // face offset in floats
        const int u0 = threadIdx.x, u1 = threadIdx.x + 256;
        const int r0 = u0 / U, c0 = u0 - r0 * U;
        const int r1 = u1 / U, c1 = u1 - r1 * U;
        const bool g0 = u0 < UR, g1 = u1 < UR;
        const int go0 = (ymn + r0) * 512 + xs + (c0 << 2);
        const int go1 = (ymn + r1) * 512 + xs + (c1 << 2);
        const int lo0 = r0 * C + (c0 << 2);
        const int lo1 = r1 * C + (c1 << 2);
        const int lA = (y0A - ymn) * C + (x0A - xs);
        const int lB = (y0B - ymn) * C + (x0B - xs);

        const float w00A = (1.f - wxA) * (1.f - wyA), w01A = wxA * (1.f - wyA);
        const float w10A = (1.f - wxA) * wyA,         w11A = wxA * wyA;
        const float w00B = (1.f - wxB) * (1.f - wyB), w01B = wxB * (1.f - wyB);
        const float w10B = (1.f - wxB) * wyB,         w11B = wxB * wyB;

        // preload round-0 window into registers
        f32x4 p0_0, p0_1, p0_2, p1_0, p1_1, p1_2;
#define PREF(K)                                                              \
        {                                                                    \
            const float* s0_ = x + IMG_FOFF((K) * 3 + 0) + fbase;            \
            const float* s1_ = x + IMG_FOFF((K) * 3 + 1) + fbase;            \
            const float* s2_ = x + IMG_FOFF((K) * 3 + 2) + fbase;            \
            if (g0) {                                                        \
                p0_0 = *(const f32x4*)(s0_ + go0);                           \
                p0_1 = *(const f32x4*)(s1_ + go0);                           \
                p0_2 = *(const f32x4*)(s2_ + go0);                           \
            }                                                                \
            if (g1) {                                                        \
                p1_0 = *(const f32x4*)(s0_ + go1);                           \
                p1_1 = *(const f32x4*)(s1_ + go1);                           \
                p1_2 = *(const f32x4*)(s2_ + go1);                           \
            }                                                                \
        }
        PREF(0)

#pragma unroll
        for (int k = 0; k < 4; ++k) {
            // write LDS from the prefetched regs
            if (g0) {
                *((f32x4*)&slds[0][lo0]) = p0_0;
                *((f32x4*)&slds[1][lo0]) = p0_1;
                *((f32x4*)&slds[2][lo0]) = p0_2;
            }
            if (g1) {
                *((f32x4*)&slds[0][lo1]) = p1_0;
                *((f32x4*)&slds[1][lo1]) = p1_1;
                *((f32x4*)&slds[2][lo1]) = p1_2;
            }
            __syncthreads();
            // issue next round's loads NOW; they complete under compute +
            // the trailing barrier. sched_barrier pins them above compute.
            if (k < 3) {
                switch (k) {
                case 0: PREF(1) break;
                case 1: PREF(2) break;
                default: PREF(3) break;
                }
                __builtin_amdgcn_sched_barrier(0);
            }
#pragma unroll
            for (int r = 0; r < 3; ++r) {
                const int i = k * 3 + r;
                const float* L = slds[r];
                const float a00 = L[lA], a01 = L[lA + 1];
                const float a10 = L[lA + C], a11 = L[lA + C + 1];
                const float b00 = L[lB], b01 = L[lB + 1];
                const float b10 = L[lB + C], b11 = L[lB + C + 1];
                f32x2 st;
                st.x = a00 * w00A + a01 * w01A + a10 * w10A + a11 * w11A;
                st.y = b00 * w00B + b01 * w01B + b10 * w10B + b11 * w11B;
                __builtin_nontemporal_store(st, (f32x2*)(out + (size_t)i * HW) + pidx);
            }
            __syncthreads();
        }
        return;
#undef PREF
    }

    // ===================== fallback: exact round-6 body =====================
    const int  xmw    = min(x0A, x0B);
    const bool compat = (fA == fB) && (y0A == y0B)
                     && ((max(x0A, x0B) - xmw) <= 2);
    const int xm  = min(compat ? xmw : x0A, 508);
    const int oAw = x0A - xm;
    const int oBw = min(max(x0B - xm, 0), 2);

    const uint32_t vbW = (uint32_t)(fA * 3145728 + y0A * 2048 + xm * 4);
    const uint32_t vbB = (uint32_t)(fB * 3145728 + y0B * 2048 + x0B * 4);

    const float aL = 1.f - wxA, aR = wxA;
    const float bL = 1.f - wxB, bR = wxB;
    f32x4 WA, WB;
    WA.x = (oAw == 0) ? aL : 0.f;
    WA.y = (oAw == 0) ? aR : ((oAw == 1) ? aL : 0.f);
    WA.z = (oAw == 2) ? aL : ((oAw == 1) ? aR : 0.f);
    WA.w = (oAw == 2) ? aR : 0.f;
    WB.x = (oBw == 0) ? bL : 0.f;
    WB.y = (oBw == 0) ? bR : ((oBw == 1) ? bL : 0.f);
    WB.z = (oBw == 2) ? bL : ((oBw == 1) ? bR : 0.f);
    WB.w = (oBw == 2) ? bR : 0.f;
    const f32x4 WA0 = WA * (1.f - wyA), WA1 = WA * wyA;
    const f32x4 WB0 = WB * (1.f - wyB), WB1 = WB * wyB;
    const float c00 = bL * (1.f - wyB), c01 = bR * (1.f - wyB);
    const float c10 = bL * wyB,         c11 = bR * wyB;

#define EMIT2(i, R0, R1, Q0, Q1)                                             \
    {                                                                        \
        const float ovA = R0.x * WA0.x + R0.y * WA0.y + R0.z * WA0.z         \
                        + R0.w * WA0.w + R1.x * WA1.x + R1.y * WA1.y         \
                        + R1.z * WA1.z + R1.w * WA1.w;                       \
        const float oBw2 = R0.x * WB0.x + R0.y * WB0.y + R0.z * WB0.z        \
                        + R0.w * WB0.w + R1.x * WB1.x + R1.y * WB1.y         \
                        + R1.z * WB1.z + R1.w * WB1.w;                       \
        const float oBf = Q0.x * c00 + Q0.y * c01 + Q1.x * c10 + Q1.y * c11; \
        f32x2 st;                                                            \
        st.x = ovA;                                                          \
        st.y = compat ? oBw2 : oBf;                                          \
        __builtin_nontemporal_store(st, (f32x2*)(out + (size_t)(i) * HW) + pidx); \
    }

#define ROUND(I0)                                                            \
    {                                                                        \
        f32x4 r0_0, r1_0, r0_1, r1_1, r0_2, r1_2,                            \
              r0_3, r1_3, r0_4, r1_4, r0_5, r1_5;                            \
        asm volatile(                                                        \
            "global_load_dwordx4 %[a0], %[vb], %[s0]\n\t"                    \
            "global_load_dwordx4 %[b0], %[vb], %[s0] offset:2048\n\t"        \
            "global_load_dwordx4 %[a1], %[vb], %[s1]\n\t"                    \
            "global_load_dwordx4 %[b1], %[vb], %[s1] offset:2048\n\t"        \
            "global_load_dwordx4 %[a2], %[vb], %[s2]\n\t"                    \
            "global_load_dwordx4 %[b2], %[vb], %[s2] offset:2048\n\t"        \
            "global_load_dwordx4 %[a3], %[vb], %[s3]\n\t"                    \
            "global_load_dwordx4 %[b3], %[vb], %[s3] offset:2048\n\t"        \
            "global_load_dwordx4 %[a4], %[vb], %[s4]\n\t"                    \
            "global_load_dwordx4 %[b4], %[vb], %[s4] offset:2048\n\t"        \
            "global_load_dwordx4 %[a5], %[vb], %[s5]\n\t"                    \
            "global_load_dwordx4 %[b5], %[vb], %[s5] offset:2048"            \
            : [a0] "=&v"(r0_0), [b0] "=&v"(r1_0),                            \
              [a1] "=&v"(r0_1), [b1] "=&v"(r1_1),                            \
              [a2] "=&v"(r0_2), [b2] "=&v"(r1_2),                            \
              [a3] "=&v"(r0_3), [b3] "=&v"(r1_3),                            \
              [a4] "=&v"(r0_4), [b4] "=&v"(r1_4),                            \
              [a5] "=&v"(r0_5), [b5] "=&v"(r1_5)                             \
            : [vb] "v"(vbW),                                                 \
              [s0] "s"(xb + IMG_OFF((I0) + 0)),                              \
              [s1] "s"(xb + IMG_OFF((I0) + 1)),                              \
              [s2] "s"(xb + IMG_OFF((I0) + 2)),                              \
              [s3] "s"(xb + IMG_OFF((I0) + 3)),                              \
              [s4] "s"(xb + IMG_OFF((I0) + 4)),                              \
              [s5] "s"(xb + IMG_OFF((I0) + 5)));                             \
        f32x2 q0_0 = {0.f, 0.f}, q1_0 = {0.f, 0.f};                          \
        f32x2 q0_1 = {0.f, 0.f}, q1_1 = {0.f, 0.f};                          \
        f32x2 q0_2 = {0.f, 0.f}, q1_2 = {0.f, 0.f};                          \
        f32x2 q0_3 = {0.f, 0.f}, q1_3 = {0.f, 0.f};                          \
        f32x2 q0_4 = {0.f, 0.f}, q1_4 = {0.f, 0.f};                          \
        f32x2 q0_5 = {0.f, 0.f}, q1_5 = {0.f, 0.f};                          \
        if (!compat) {                                                       \
            asm volatile(                                                    \
                "global_load_dwordx2 %[a0], %[vb], %[s0]\n\t"                \
                "global_load_dwordx2 %[b0], %[vb], %[s0] offset:2048\n\t"    \
                "global_load_dwordx2 %[a1], %[vb], %[s1]\n\t"                \
                "global_load_dwordx2 %[b1], %[vb], %[s1] offset:2048\n\t"    \
                "global_load_dwordx2 %[a2], %[vb], %[s2]\n\t"                \
                "global_load_dwordx2 %[b2], %[vb], %[s2] offset:2048\n\t"    \
                "global_load_dwordx2 %[a3], %[vb], %[s3]\n\t"                \
                "global_load_dwordx2 %[b3], %[vb], %[s3] offset:2048\n\t"    \
                "global_load_dwordx2 %[a4], %[vb], %[s4]\n\t"                \
                "global_load_dwordx2 %[b4], %[vb], %[s4] offset:2048\n\t"    \
                "global_load_dwordx2 %[a5], %[vb], %[s5]\n\t"                \
                "global_load_dwordx2 %[b5], %[vb], %[s5] offset:2048"        \
                : [a0] "=&v"(q0_0), [b0] "=&v"(q1_0),                        \
                  [a1] "=&v"(q0_1), [b1] "=&v"(q1_1),                        \
                  [a2] "=&v"(q0_2), [b2] "=&v"(q1_2),                        \
                  [a3] "=&v"(q0_3), [b3] "=&v"(q1_3),                        \
                  [a4] "=&v"(q0_4), [b4] "=&v"(q1_4),                        \
                  [a5] "=&v"(q0_5), [b5] "=&v"(q1_5)                         \
                : [vb] "v"(vbB),                                             \
                  [s0] "s"(xb + IMG_OFF((I0) + 0)),                          \
                  [s1] "s"(xb + IMG_OFF((I0) + 1)),                          \
                  [s2] "s"(xb + IMG_OFF((I0) + 2)),                          \
                  [s3] "s"(xb + IMG_OFF((I0) + 3)),                          \
                  [s4] "s"(xb + IMG_OFF((I0) + 4)),                          \
                  [s5] "s"(xb + IMG_OFF((I0) + 5)));                         \
        }                                                                    \
        asm volatile("s_waitcnt vmcnt(0)" ::: "memory");                     \
        __builtin_amdgcn_sched_barrier(0);                                   \
        EMIT2((I0) + 0, r0_0, r1_0, q0_0, q1_0)                              \
        EMIT2((I0) + 1, r0_1, r1_1, q0_1, q1_1)                              \
        EMIT2((I0) + 2, r0_2, r1_2, q0_2, q1_2)                              \
        EMIT2((I0) + 3, r0_3, r1_3, q0_3, q1_3)                              \
        EMIT2((I0) + 4, r0_4, r1_4, q0_4, q1_4)                              \
        EMIT2((I0) + 5, r0_5, r1_5, q0_5, q1_5)                              \
    }

    ROUND(0)
    ROUND(6)

#undef ROUND
#undef EMIT2
}

extern "C" void kernel_launch(void* const* d_in, const int* in_sizes, int n_in,
                              void* d_out, int out_size, void* d_ws, size_t ws_size,
                              hipStream_t stream) {
    const float* x    = (const float*)d_in[0];
    const float* uv   = (const float*)d_in[1];
    const int*   face = (const int*)d_in[2];
    float*       out  = (float*)d_out;

    const int grid = 64 * 64;  // 4096 tiles of 32x16 px, column-major order
    hipLaunchKernelGGL(cube2equirec_kernel, dim3(grid), dim3(256), 0, stream,
                       x, uv, face, out);
}